// Round 1
// baseline (156.643 us; speedup 1.0000x reference)
//
#include <hip/hip_runtime.h>

#define HH 1024
#define WW 1024
#define RPT 16   // output rows per thread
#define JPT 4    // output cols per thread (float4)

__global__ __launch_bounds__(256) void diamond_kernel(const float* __restrict__ in,
                                                      float* __restrict__ out) {
    const int tj = threadIdx.x;          // 0..63  (column groups)
    const int ty = threadIdx.y;          // 0..3   (row strips)
    const int b  = blockIdx.z;
    const int j0 = (blockIdx.x * 64 + tj) * JPT;      // first output column
    const int i0 = (blockIdx.y * 4 + ty) * RPT;       // first output row
    const float* __restrict__ src = in  + (size_t)b * HH * WW;
    float*       __restrict__ dst = out + (size_t)b * HH * WW;

    const float EV[6] = {1.0f,
                         0.36787944117144233f,   // e^-1
                         0.1353352832366127f,    // e^-2
                         0.049787068367863944f,  // e^-3
                         0.018315638888734179f,  // e^-4
                         0.006737946999085467f}; // e^-5

    float acc[RPT][JPT];
#pragma unroll
    for (int m = 0; m < RPT; ++m)
#pragma unroll
        for (int p = 0; p < JPT; ++p) acc[m][p] = 0.0f;

#pragma unroll
    for (int rr = 0; rr < RPT + 10; ++rr) {
        const int ri = (i0 + rr - 5) & (HH - 1);       // circular row
        const float* row = src + (size_t)ri * WW;

        // load 20 contiguous floats covering columns j0-8 .. j0+11
        // chunk bases are 4-aligned; 1024 % 4 == 0 so & (WW-1) wraps whole chunks
        float4 c[5];
#pragma unroll
        for (int t = 0; t < 5; ++t) {
            const int cb = (j0 - 8 + 4 * t) & (WW - 1);
            c[t] = *reinterpret_cast<const float4*>(row + cb);
        }
        float s[20];
#pragma unroll
        for (int t = 0; t < 5; ++t) {
            s[4 * t + 0] = c[t].x;
            s[4 * t + 1] = c[t].y;
            s[4 * t + 2] = c[t].z;
            s[4 * t + 3] = c[t].w;
        }

        // horizontal partial sums H_k, k=0..5, for the 4 output columns
        float Hk[6][JPT];
#pragma unroll
        for (int p = 0; p < JPT; ++p) Hk[0][p] = s[8 + p];
#pragma unroll
        for (int k = 1; k <= 5; ++k) {
#pragma unroll
            for (int p = 0; p < JPT; ++p)
                Hk[k][p] = fmaf(EV[k], s[8 + p - k] + s[8 + p + k], Hk[k - 1][p]);
        }

        // vertical accumulation: this input row is output row (i0+m) + o, o = rr-5-m
#pragma unroll
        for (int m = 0; m < RPT; ++m) {
            if (m > rr || m < rr - 10) continue;   // compile-time pruned after unroll
            const int o = rr - 5 - m;
            const int a = o < 0 ? -o : o;
            if (a == 0) {
                // center row: weight 1, and remove the (0,0) self term exactly
#pragma unroll
                for (int p = 0; p < JPT; ++p)
                    acc[m][p] += Hk[5][p] - s[8 + p];
            } else {
#pragma unroll
                for (int p = 0; p < JPT; ++p)
                    acc[m][p] = fmaf(EV[a], Hk[5 - a][p], acc[m][p]);
            }
        }
    }

#pragma unroll
    for (int m = 0; m < RPT; ++m) {
        float4 v = make_float4(acc[m][0], acc[m][1], acc[m][2], acc[m][3]);
        *reinterpret_cast<float4*>(dst + (size_t)(i0 + m) * WW + j0) = v;
    }
}

extern "C" void kernel_launch(void* const* d_in, const int* in_sizes, int n_in,
                              void* d_out, int out_size, void* d_ws, size_t ws_size,
                              hipStream_t stream) {
    const float* in  = (const float*)d_in[0];
    float*       out = (float*)d_out;
    const int B = in_sizes[0] / (HH * WW);   // 64
    dim3 block(64, 4, 1);
    dim3 grid(WW / (64 * JPT), HH / (4 * RPT), B);
    hipLaunchKernelGGL(diamond_kernel, grid, block, 0, stream, in, out);
}